// Round 5
// baseline (162.620 us; speedup 1.0000x reference)
//
#include <hip/hip_runtime.h>
#include <math.h>

#define Bsz 1024
#define Dd  256
#define Hh  512
#define NOUT 8192       // D*K, K=32

typedef __attribute__((ext_vector_type(8))) short bf8_t;   // 8 bf16 (4 VGPRs)
typedef __attribute__((ext_vector_type(4))) float f4_t;    // 4 fp32

__device__ inline ushort f2b(float f) {
  union { float f; unsigned u; } c; c.f = f;
  unsigned r = c.u + 0x7fffu + ((c.u >> 16) & 1u);   // RNE
  return (ushort)(r >> 16);
}

__device__ inline void async16(const ushort* g, ushort* l) {
  __builtin_amdgcn_global_load_lds((const __attribute__((address_space(1))) void*)g,
                                   (__attribute__((address_space(3))) void*)l, 16, 0, 0);
}

__device__ inline int mod255(int v) {   // valid for v in [0, 765)
  if (v >= 510) return v - 510;
  if (v >= 255) return v - 255;
  return v;
}

// ---------- prep: fp32 -> bf16 (+mask) for W0, W1, W2, Wout; block 2368 does lpa -------
// (x conversion moved into mlp3's staging; grid = 64+128+128+2048+1 = 2369)
__global__ __launch_bounds__(256) void prep(
    const float* __restrict__ W0, const float* __restrict__ W1,
    const float* __restrict__ W2, const float* __restrict__ Wout,
    const float* __restrict__ ulpa,
    ushort* __restrict__ w0b, ushort* __restrict__ w1b,
    ushort* __restrict__ w2b, ushort* __restrict__ woutb,
    float* __restrict__ lpa)
{
  const int blk = blockIdx.x, tid = threadIdx.x;
  if (blk == 2368) {
    if (tid < Dd - 1) {
      float v0 = ulpa[tid * 4 + 0], v1 = ulpa[tid * 4 + 1];
      float v2 = ulpa[tid * 4 + 2], v3 = ulpa[tid * 4 + 3];
      float m = fmaxf(fmaxf(v0, v1), fmaxf(v2, v3));
      float s = __expf(v0 - m) + __expf(v1 - m) + __expf(v2 - m) + __expf(v3 - m);
      float l = m + __logf(s);
      lpa[tid * 4 + 0] = v0 - l;
      lpa[tid * 4 + 1] = v1 - l;
      lpa[tid * 4 + 2] = v2 - l;
      lpa[tid * 4 + 3] = v3 - l;
    }
    return;
  }
  const float* src; ushort* dst; int lb, mode;
  if (blk < 64)       { src = W0;   dst = w0b;   lb = blk;       mode = 1; }
  else if (blk < 192) { src = W1;   dst = w1b;   lb = blk - 64;  mode = 2; }
  else if (blk < 320) { src = W2;   dst = w2b;   lb = blk - 192; mode = 2; }
  else                { src = Wout; dst = woutb; lb = blk - 320; mode = 3; }

  const int e = lb * 2048 + tid * 8;
  float4 v0 = *(const float4*)(src + e);
  float4 v1 = *(const float4*)(src + e + 4);
  float vv[8] = {v0.x, v0.y, v0.z, v0.w, v1.x, v1.y, v1.z, v1.w};
  ushort u[8];
  if (mode == 1) {                   // Kd=256: (n%255) >= k
    int n = e >> 8, k0 = e & 255, nd = mod255(n);
#pragma unroll
    for (int i = 0; i < 8; i++) u[i] = (nd >= k0 + i) ? f2b(vv[i]) : (ushort)0;
  } else if (mode == 2) {            // Kd=512: (n%255) >= (k%255)
    int n = e >> 9, k0 = e & 511, nd = mod255(n);
#pragma unroll
    for (int i = 0; i < 8; i++) u[i] = (nd >= mod255(k0 + i)) ? f2b(vv[i]) : (ushort)0;
  } else {                           // Kd=512: (n>>5)-1 >= (k%255)
    int n = e >> 9, k0 = e & 511, nd = (n >> 5) - 1;
#pragma unroll
    for (int i = 0; i < 8; i++) u[i] = (nd >= mod255(k0 + i)) ? f2b(vv[i]) : (ushort)0;
  }
  *(ushort4*)(dst + e)     = *(ushort4*)&u[0];
  *(ushort4*)(dst + e + 4) = *(ushort4*)&u[4];
}

// ---------- fused MLP layer: 16 rows (LDS, swizzled) x all 512 cols, W from global -----
// A-fragment from LDS (gemm_s layout: [kt][16 rows][64], chunk q at slot (q+row)&7);
// B-fragment streamed global->VGPR (16B per lane, L2-resident weights).
template<int KD, bool TO_GLOBAL>
__device__ __forceinline__ void mlp_layer(
    const ushort* hin, const ushort* __restrict__ Wg,
    const float* __restrict__ bias, ushort* hout,
    int row0, int lane, int wave)
{
  const int fm = lane & 15, qq = lane >> 4;
#pragma unroll
  for (int ct = 0; ct < 4; ct++) {
    const int n0 = wave * 64 + ct * 16;
    const ushort* wrow = Wg + (size_t)(n0 + fm) * KD;
    f4_t acc = (f4_t){0.f, 0.f, 0.f, 0.f};
#pragma unroll
    for (int kt = 0; kt < KD / 64; kt++) {
#pragma unroll
      for (int t = 0; t < 2; t++) {
        const int c = t * 4 + qq;
        bf8_t af = *(const bf8_t*)&hin[(kt * 16 + fm) * 64 + ((c + fm) & 7) * 8];
        bf8_t bf = *(const bf8_t*)(wrow + kt * 64 + c * 8);
        acc = __builtin_amdgcn_mfma_f32_16x16x32_bf16(af, bf, acc, 0, 0, 0);
      }
    }
    const int col = n0 + fm;
    const float bv = bias[col];
#pragma unroll
    for (int r = 0; r < 4; r++) {
      const int row = qq * 4 + r;
      float tv = fmaxf(acc[r] + bv, 0.0f);
      ushort hv = f2b(tv);
      if (TO_GLOBAL) {
        hout[(size_t)(row0 + row) * Hh + col] = hv;
      } else {
        const int kt2 = col >> 6, q2 = (col >> 3) & 7, w2 = col & 7;
        hout[(kt2 * 16 + row) * 64 + ((q2 + row) & 7) * 8 + w2] = hv;
      }
    }
  }
}

// ---------- mlp3: L0+L1+L2 fused per 16-row block (64 blocks x 512 thr) ----------------
// h2[1024,512] = relu(relu(relu(x@W0m^T+b0)@W1m^T+b1)@W2m^T+b2); h tiles never leave LDS.
__global__ __launch_bounds__(512) void mlp3(
    const float* __restrict__ x,
    const ushort* __restrict__ w0b, const float* __restrict__ b0,
    const ushort* __restrict__ w1b, const float* __restrict__ b1,
    const ushort* __restrict__ w2b, const float* __restrict__ b2,
    ushort* __restrict__ h2)
{
  __shared__ ushort hA[8 * 16 * 64];    // 16 KB, holds x (K=256) then h1 (K=512)
  __shared__ ushort hB[8 * 16 * 64];    // 16 KB, holds h0 (K=512 layout)
  const int tid = threadIdx.x, lane = tid & 63, wave = tid >> 6;
  const int row0 = blockIdx.x * 16;

  // ---- stage x: 16 x 256 fp32 -> bf16, swizzled into hA (1024 float4, 2/thread) ----
#pragma unroll
  for (int it = 0; it < 2; it++) {
    int f = it * 512 + tid;
    int r = f >> 6, k4 = (f & 63) << 2;
    float4 v = *(const float4*)(x + (size_t)(row0 + r) * Dd + k4);
    ushort4 u;
    u.x = f2b(v.x); u.y = f2b(v.y); u.z = f2b(v.z); u.w = f2b(v.w);
    int t = k4 >> 6, q = (k4 >> 3) & 7, half = (k4 >> 2) & 1;
    *(ushort4*)&hA[(t * 16 + r) * 64 + ((q + r) & 7) * 8 + half * 4] = u;
  }
  __syncthreads();

  mlp_layer<Dd, false>(hA, w0b, b0, hB, row0, lane, wave);   // h0 -> hB
  __syncthreads();
  mlp_layer<Hh, false>(hB, w1b, b1, hA, row0, lane, wave);   // h1 -> hA
  __syncthreads();
  mlp_layer<Hh, true >(hA, w2b, b2, h2, row0, lane, wave);   // h2 -> global
}

// ---------- big bf16 MFMA GEMM (128x128 tile), double-buffered, fp32 out ---------------
__global__ __launch_bounds__(256) void gemm_big(
    const ushort* __restrict__ A, const ushort* __restrict__ W,
    const float* __restrict__ bias, float* __restrict__ Cf,
    int M, int N, int Kd)
{
  __shared__ ushort As[2][128 * 64];
  __shared__ ushort Bs[2][128 * 64];
  const int tid = threadIdx.x, lane = tid & 63, wave = tid >> 6;
  const int waveM = wave >> 1, waveN = wave & 1;
  const int row0 = blockIdx.y * 128, col0 = blockIdx.x * 128;
  const int fm = lane & 15, qq = lane >> 4;
  const int srow = lane >> 3, qslot = lane & 7;

  f4_t acc[4][4];
#pragma unroll
  for (int i = 0; i < 4; i++)
#pragma unroll
    for (int j = 0; j < 4; j++) acc[i][j] = (f4_t){0.f, 0.f, 0.f, 0.f};

  auto stage = [&](int buf, int kt) {        // 8 global_load_lds per wave
#pragma unroll
    for (int p = 0; p < 4; p++) {
      int rb = p * 32 + wave * 8;
      int r = rb + srow;
      int q = (qslot - r) & 7;
      async16(A + (size_t)(row0 + r) * Kd + kt + q * 8, &As[buf][rb * 64]);
    }
#pragma unroll
    for (int p = 0; p < 4; p++) {
      int rb = p * 32 + wave * 8;
      int r = rb + srow;
      int q = (qslot - r) & 7;
      async16(W + (size_t)(col0 + r) * Kd + kt + q * 8, &Bs[buf][rb * 64]);
    }
  };

  stage(0, 0);
  int cur = 0;
  for (int kt = 0; kt < Kd; kt += 64) {
    asm volatile("s_waitcnt vmcnt(0)" ::: "memory");   // current tile landed
    __builtin_amdgcn_s_barrier();
    asm volatile("" ::: "memory");
    if (kt + 64 < Kd) stage(cur ^ 1, kt + 64);         // overlap next stage w/ compute
#pragma unroll
    for (int t = 0; t < 2; t++) {
      bf8_t af[4], bf[4];
#pragma unroll
      for (int i = 0; i < 4; i++) {
        int r = waveM * 64 + i * 16 + fm;
        int slot = ((t * 4 + qq) + r) & 7;
        af[i] = *(const bf8_t*)&As[cur][r * 64 + slot * 8];
      }
#pragma unroll
      for (int j = 0; j < 4; j++) {
        int r = waveN * 64 + j * 16 + fm;
        int slot = ((t * 4 + qq) + r) & 7;
        bf[j] = *(const bf8_t*)&Bs[cur][r * 64 + slot * 8];
      }
#pragma unroll
      for (int i = 0; i < 4; i++)
#pragma unroll
        for (int j = 0; j < 4; j++)
          acc[i][j] = __builtin_amdgcn_mfma_f32_16x16x32_bf16(af[i], bf[j], acc[i][j], 0, 0, 0);
    }
    asm volatile("s_waitcnt lgkmcnt(0)" ::: "memory");
    cur ^= 1;
  }

#pragma unroll
  for (int j = 0; j < 4; j++) {
    int col = col0 + waveN * 64 + j * 16 + fm;
    float bv = bias[col];
#pragma unroll
    for (int i = 0; i < 4; i++) {
      int rbase = row0 + waveM * 64 + i * 16 + qq * 4;
#pragma unroll
      for (int r = 0; r < 4; r++)
        Cf[(size_t)(rbase + r) * N + col] = acc[i][j][r] + bv;
    }
  }
}

// ---------------- chain: LDS-staged, 32 segments, tree-combined 4x4 log-semiring -------
__global__ __launch_bounds__(512) void chain2(
    const float* __restrict__ x, const float* __restrict__ theta,
    const float* __restrict__ lpa, float* __restrict__ logp)
{
  __shared__ float ths[256 * 33];       // theta row, pitch 33
  __shared__ float xs[256];
  __shared__ float lps[255 * 5];        // lpa, pitch 5
  __shared__ float TA[32][16];
  __shared__ float TB[16][16];

  const int b = blockIdx.x;
  const int tid = threadIdx.x;
  const float C0 = 0.91893853320467274178f;     // 0.5*log(2*pi)

  // ---- cooperative stage: theta row (32KB), x row, lpa ----
  const float4* src = (const float4*)(theta + (size_t)b * NOUT);
#pragma unroll
  for (int it = 0; it < 4; it++) {
    int t = tid + it * 512;                     // 2048 float4 total
    float4 v = src[t];
    int d = t >> 3, c = (t & 7) * 4;
    float* p = &ths[d * 33 + c];
    p[0] = v.x; p[1] = v.y; p[2] = v.z; p[3] = v.w;
  }
  if (tid < 64) ((float4*)xs)[tid] = ((const float4*)(x + (size_t)b * Dd))[tid];
  if (tid < 255) {
    float4 v = ((const float4*)lpa)[tid];
    float* p = &lps[tid * 5];
    p[0] = v.x; p[1] = v.y; p[2] = v.z; p[3] = v.w;
  }
  __syncthreads();

  // ---- phase 1: 32 segments x ~8 steps, 16 threads per segment ----
  const int seg = tid >> 4, e = tid & 15, ii = e >> 2, jj = e & 3;
  const int base = (tid & 63) & ~15;
  const int d0 = 1 + seg * 8;
  const int d1 = min(d0 + 8, Dd - 1);

  auto stepm = [&](int d) -> float {
    float mu = ths[d * 33 + e];
    float ls = ths[d * 33 + 16 + e];
    float s  = __expf(ls) + 0.01f;
    float z  = (xs[d] - mu) * __builtin_amdgcn_rcpf(s);
    return -0.5f * z * z - __logf(s) - C0 + lps[d * 5 + jj];
  };

  float T = stepm(d0);
  for (int d = d0 + 1; d < d1; d++) {
    float m_ = stepm(d);
    float v0 = __shfl(T, base + ii * 4 + 0) + __shfl(m_, base + 0 * 4 + jj);
    float v1 = __shfl(T, base + ii * 4 + 1) + __shfl(m_, base + 1 * 4 + jj);
    float v2 = __shfl(T, base + ii * 4 + 2) + __shfl(m_, base + 2 * 4 + jj);
    float v3 = __shfl(T, base + ii * 4 + 3) + __shfl(m_, base + 3 * 4 + jj);
    float mx = fmaxf(fmaxf(v0, v1), fmaxf(v2, v3));
    float s  = __expf(v0 - mx) + __expf(v1 - mx) + __expf(v2 - mx) + __expf(v3 - mx);
    T = mx + __logf(s);
  }
  TA[seg][e] = T;
  __syncthreads();

  // ---- phase 2: binary tree of 4x4 log-semiring matrix products (32 -> 1) ----
  float (*cur)[16] = TA;
  float (*nxt)[16] = TB;
#pragma unroll
  for (int n = 16; n >= 1; n >>= 1) {
    if (tid < n * 16) {
      int p = tid >> 4, ee = tid & 15, i2 = ee >> 2, j2 = ee & 3;
      const float* L = cur[2 * p];
      const float* R = cur[2 * p + 1];
      float v0 = L[i2 * 4 + 0] + R[0 * 4 + j2];
      float v1 = L[i2 * 4 + 1] + R[1 * 4 + j2];
      float v2 = L[i2 * 4 + 2] + R[2 * 4 + j2];
      float v3 = L[i2 * 4 + 3] + R[3 * 4 + j2];
      float mx = fmaxf(fmaxf(v0, v1), fmaxf(v2, v3));
      float ss = __expf(v0 - mx) + __expf(v1 - mx) + __expf(v2 - mx) + __expf(v3 - mx);
      nxt[p][ee] = mx + __logf(ss);
    }
    __syncthreads();
    float (*tmp)[16] = cur; cur = nxt; nxt = tmp;
  }

  // ---- final: logp = LSE_{i,j}( first[i] + P[i][j] + last[j] ) ----
  if (tid < 16) {
    int i = tid >> 2, j = tid & 3;
    float mu0 = ths[i], ls0 = ths[16 + i];                   // d=0, row 0, col i
    float s0 = __expf(ls0) + 0.01f;
    float z0 = (xs[0] - mu0) * __builtin_amdgcn_rcpf(s0);
    float c0 = -0.5f * z0 * z0 - __logf(s0) - C0 + lps[i];
    float muL = ths[255 * 33 + j * 4];                       // d=255, row j, col 0
    float lsL = ths[255 * 33 + 16 + j * 4];
    float sL = __expf(lsL) + 0.01f;
    float zL = (xs[255] - muL) * __builtin_amdgcn_rcpf(sL);
    float lL = -0.5f * zL * zL - __logf(sL) - C0;
    float v = c0 + cur[0][tid] + lL;
    float mx = fmaxf(v, __shfl_xor(v, 1));
    mx = fmaxf(mx, __shfl_xor(mx, 2));
    mx = fmaxf(mx, __shfl_xor(mx, 4));
    mx = fmaxf(mx, __shfl_xor(mx, 8));
    float ee = __expf(v - mx);
    ee += __shfl_xor(ee, 1);
    ee += __shfl_xor(ee, 2);
    ee += __shfl_xor(ee, 4);
    ee += __shfl_xor(ee, 8);
    if (tid == 0) logp[b] = mx + __logf(ee);
  }
}

extern "C" void kernel_launch(void* const* d_in, const int* in_sizes, int n_in,
                              void* d_out, int out_size, void* d_ws, size_t ws_size,
                              hipStream_t stream)
{
  const float* x    = (const float*)d_in[0];
  const float* W0   = (const float*)d_in[1];
  const float* b0   = (const float*)d_in[2];
  const float* W1   = (const float*)d_in[3];
  const float* b1   = (const float*)d_in[4];
  const float* W2   = (const float*)d_in[5];
  const float* b2   = (const float*)d_in[6];
  const float* Wout = (const float*)d_in[7];
  const float* bout = (const float*)d_in[8];
  const float* ulpa = (const float*)d_in[9];

  float* out   = (float*)d_out;
  float* logp  = out;               // (B,1,1)
  float* theta = out + Bsz;         // (B,D,2,A,A) fp32

  ushort* ws    = (ushort*)d_ws;
  ushort* w0b   = ws;                       // 131072
  ushort* w1b   = w0b + 131072;             // 262144
  ushort* w2b   = w1b + 262144;             // 262144
  ushort* woutb = w2b + 262144;             // 4194304
  ushort* h2    = woutb + 4194304;          // 524288
  float*  lpa   = (float*)(h2 + 524288);    // 1020 floats (pad to 1024)

  // 4 kernels: prep -> mlp3 (L0+L1+L2 row-block fused) -> gemm_big -> chain2
  prep<<<2369, 256, 0, stream>>>(W0, W1, W2, Wout, ulpa,
                                 w0b, w1b, w2b, woutb, lpa);
  mlp3<<<64, 512, 0, stream>>>(x, w0b, b0, w1b, b1, w2b, b2, h2);
  gemm_big<<<dim3(NOUT / 128, Bsz / 128), 256, 0, stream>>>(
      h2, woutb, bout, theta, Bsz, NOUT, Hh);
  chain2<<<Bsz, 512, 0, stream>>>(x, theta, lpa, logp);
}

// Round 7
// 137.598 us; speedup vs baseline: 1.1818x; 1.1818x over previous
//
#include <hip/hip_runtime.h>
#include <math.h>

#define Bsz 1024
#define Dd  256
#define Hh  512
#define NOUT 8192       // D*K, K=32

typedef __attribute__((ext_vector_type(8))) short bf8_t;   // 8 bf16 (4 VGPRs)
typedef __attribute__((ext_vector_type(4))) float f4_t;    // 4 fp32

__device__ inline ushort f2b(float f) {
  union { float f; unsigned u; } c; c.f = f;
  unsigned r = c.u + 0x7fffu + ((c.u >> 16) & 1u);   // RNE
  return (ushort)(r >> 16);
}

__device__ inline void async16(const ushort* g, ushort* l) {
  __builtin_amdgcn_global_load_lds((const __attribute__((address_space(1))) void*)g,
                                   (__attribute__((address_space(3))) void*)l, 16, 0, 0);
}

__device__ inline int mod255(int v) {   // valid for v in [0, 765)
  if (v >= 510) return v - 510;
  if (v >= 255) return v - 255;
  return v;
}

// ---------- prep: fp32 -> bf16 (+mask) for x, W0, W1, W2, Wout; block 2496 does lpa ----
__global__ __launch_bounds__(256) void prep(
    const float* __restrict__ x,  const float* __restrict__ W0,
    const float* __restrict__ W1, const float* __restrict__ W2,
    const float* __restrict__ Wout, const float* __restrict__ ulpa,
    ushort* __restrict__ xb, ushort* __restrict__ w0b, ushort* __restrict__ w1b,
    ushort* __restrict__ w2b, ushort* __restrict__ woutb,
    float* __restrict__ lpa)
{
  const int blk = blockIdx.x, tid = threadIdx.x;
  if (blk == 2496) {
    if (tid < Dd - 1) {
      float v0 = ulpa[tid * 4 + 0], v1 = ulpa[tid * 4 + 1];
      float v2 = ulpa[tid * 4 + 2], v3 = ulpa[tid * 4 + 3];
      float m = fmaxf(fmaxf(v0, v1), fmaxf(v2, v3));
      float s = __expf(v0 - m) + __expf(v1 - m) + __expf(v2 - m) + __expf(v3 - m);
      float l = m + __logf(s);
      lpa[tid * 4 + 0] = v0 - l;
      lpa[tid * 4 + 1] = v1 - l;
      lpa[tid * 4 + 2] = v2 - l;
      lpa[tid * 4 + 3] = v3 - l;
    }
    return;
  }
  const float* src; ushort* dst; int lb, mode;
  if (blk < 128)      { src = x;    dst = xb;    lb = blk;       mode = 0; }
  else if (blk < 192) { src = W0;   dst = w0b;   lb = blk - 128; mode = 1; }
  else if (blk < 320) { src = W1;   dst = w1b;   lb = blk - 192; mode = 2; }
  else if (blk < 448) { src = W2;   dst = w2b;   lb = blk - 320; mode = 2; }
  else                { src = Wout; dst = woutb; lb = blk - 448; mode = 3; }

  const int e = lb * 2048 + tid * 8;
  float4 v0 = *(const float4*)(src + e);
  float4 v1 = *(const float4*)(src + e + 4);
  float vv[8] = {v0.x, v0.y, v0.z, v0.w, v1.x, v1.y, v1.z, v1.w};
  ushort u[8];
  if (mode == 0) {
#pragma unroll
    for (int i = 0; i < 8; i++) u[i] = f2b(vv[i]);
  } else if (mode == 1) {            // Kd=256: (n%255) >= k
    int n = e >> 8, k0 = e & 255, nd = mod255(n);
#pragma unroll
    for (int i = 0; i < 8; i++) u[i] = (nd >= k0 + i) ? f2b(vv[i]) : (ushort)0;
  } else if (mode == 2) {            // Kd=512: (n%255) >= (k%255)
    int n = e >> 9, k0 = e & 511, nd = mod255(n);
#pragma unroll
    for (int i = 0; i < 8; i++) u[i] = (nd >= mod255(k0 + i)) ? f2b(vv[i]) : (ushort)0;
  } else {                           // Kd=512: (n>>5)-1 >= (k%255)
    int n = e >> 9, k0 = e & 511, nd = (n >> 5) - 1;
#pragma unroll
    for (int i = 0; i < 8; i++) u[i] = (nd >= mod255(k0 + i)) ? f2b(vv[i]) : (ushort)0;
  }
  *(ushort4*)(dst + e)     = *(ushort4*)&u[0];
  *(ushort4*)(dst + e + 4) = *(ushort4*)&u[4];
}

// ---------- small layer GEMM: 32x32 tile, 512 blocks (2/CU), depth-3 pipeline ----------
// C[1024, 512] = relu(A[1024,KD] @ W[512,KD]^T + bias); all bf16, W pre-masked.
template<int KD>
__global__ __launch_bounds__(256) void gemm_s(
    const ushort* __restrict__ A, const ushort* __restrict__ W,
    const float* __restrict__ bias, ushort* __restrict__ Ch)
{
  constexpr int NT = KD / 64;                 // 4 or 8 K-tiles
  __shared__ ushort As[3][32 * 64];
  __shared__ ushort Bs[3][32 * 64];
  const int tid = threadIdx.x, lane = tid & 63, wave = tid >> 6;
  const int row0 = blockIdx.y * 32, col0 = blockIdx.x * 32;
  const int rt = wave >> 1, ct = wave & 1;    // 2x2 wave grid over the 32x32 tile
  const int fm = lane & 15, qq = lane >> 4;
  const int srow = lane >> 3, qslot = lane & 7;

  f4_t acc = (f4_t){0.f, 0.f, 0.f, 0.f};

  auto stage = [&](int buf, int kt) {         // 2 global_load_lds per wave
    {
      int rb = wave * 8;
      int r = rb + srow;
      int q = (qslot - r) & 7;
      async16(A + (size_t)(row0 + r) * KD + kt + q * 8, &As[buf][rb * 64]);
    }
    {
      int rb = wave * 8;
      int r = rb + srow;
      int q = (qslot - r) & 7;
      async16(W + (size_t)(col0 + r) * KD + kt + q * 8, &Bs[buf][rb * 64]);
    }
  };

  stage(0, 0);
  stage(1, 64);

#pragma unroll
  for (int i = 0; i < NT; i++) {
    if (i + 1 < NT) asm volatile("s_waitcnt vmcnt(2)" ::: "memory");   // tile i landed
    else            asm volatile("s_waitcnt vmcnt(0)" ::: "memory");
    __builtin_amdgcn_s_barrier();
    asm volatile("" ::: "memory");
    if (i + 2 < NT) stage((i + 2) % 3, (i + 2) * 64);
    const int buf = i % 3;
#pragma unroll
    for (int t = 0; t < 2; t++) {
      int ra = rt * 16 + fm;
      int slota = ((t * 4 + qq) + ra) & 7;
      bf8_t af = *(const bf8_t*)&As[buf][ra * 64 + slota * 8];
      int rb = ct * 16 + fm;
      int slotb = ((t * 4 + qq) + rb) & 7;
      bf8_t bf = *(const bf8_t*)&Bs[buf][rb * 64 + slotb * 8];
      acc = __builtin_amdgcn_mfma_f32_16x16x32_bf16(af, bf, acc, 0, 0, 0);
    }
    asm volatile("s_waitcnt lgkmcnt(0)" ::: "memory");
  }

  {
    int col = col0 + ct * 16 + fm;
    float bv = bias[col];
    int rbase = row0 + rt * 16 + qq * 4;
#pragma unroll
    for (int r = 0; r < 4; r++) {
      float t = fmaxf(acc[r] + bv, 0.0f);
      Ch[(size_t)(rbase + r) * Hh + col] = f2b(t);
    }
  }
}

// ---------- big bf16 MFMA GEMM (128x128 tile), double-buffered, fp32 out ---------------
__global__ __launch_bounds__(256) void gemm_big(
    const ushort* __restrict__ A, const ushort* __restrict__ W,
    const float* __restrict__ bias, float* __restrict__ Cf,
    int M, int N, int Kd)
{
  __shared__ ushort As[2][128 * 64];
  __shared__ ushort Bs[2][128 * 64];
  const int tid = threadIdx.x, lane = tid & 63, wave = tid >> 6;
  const int waveM = wave >> 1, waveN = wave & 1;
  const int row0 = blockIdx.y * 128, col0 = blockIdx.x * 128;
  const int fm = lane & 15, qq = lane >> 4;
  const int srow = lane >> 3, qslot = lane & 7;

  f4_t acc[4][4];
#pragma unroll
  for (int i = 0; i < 4; i++)
#pragma unroll
    for (int j = 0; j < 4; j++) acc[i][j] = (f4_t){0.f, 0.f, 0.f, 0.f};

  auto stage = [&](int buf, int kt) {        // 8 global_load_lds per wave
#pragma unroll
    for (int p = 0; p < 4; p++) {
      int rb = p * 32 + wave * 8;
      int r = rb + srow;
      int q = (qslot - r) & 7;
      async16(A + (size_t)(row0 + r) * Kd + kt + q * 8, &As[buf][rb * 64]);
    }
#pragma unroll
    for (int p = 0; p < 4; p++) {
      int rb = p * 32 + wave * 8;
      int r = rb + srow;
      int q = (qslot - r) & 7;
      async16(W + (size_t)(col0 + r) * Kd + kt + q * 8, &Bs[buf][rb * 64]);
    }
  };

  stage(0, 0);
  int cur = 0;
  for (int kt = 0; kt < Kd; kt += 64) {
    asm volatile("s_waitcnt vmcnt(0)" ::: "memory");   // current tile landed
    __builtin_amdgcn_s_barrier();
    asm volatile("" ::: "memory");
    if (kt + 64 < Kd) stage(cur ^ 1, kt + 64);         // overlap next stage w/ compute
#pragma unroll
    for (int t = 0; t < 2; t++) {
      bf8_t af[4], bf[4];
#pragma unroll
      for (int i = 0; i < 4; i++) {
        int r = waveM * 64 + i * 16 + fm;
        int slot = ((t * 4 + qq) + r) & 7;
        af[i] = *(const bf8_t*)&As[cur][r * 64 + slot * 8];
      }
#pragma unroll
      for (int j = 0; j < 4; j++) {
        int r = waveN * 64 + j * 16 + fm;
        int slot = ((t * 4 + qq) + r) & 7;
        bf[j] = *(const bf8_t*)&Bs[cur][r * 64 + slot * 8];
      }
#pragma unroll
      for (int i = 0; i < 4; i++)
#pragma unroll
        for (int j = 0; j < 4; j++)
          acc[i][j] = __builtin_amdgcn_mfma_f32_16x16x32_bf16(af[i], bf[j], acc[i][j], 0, 0, 0);
    }
    asm volatile("s_waitcnt lgkmcnt(0)" ::: "memory");
    cur ^= 1;
  }

#pragma unroll
  for (int j = 0; j < 4; j++) {
    int col = col0 + waveN * 64 + j * 16 + fm;
    float bv = bias[col];
#pragma unroll
    for (int i = 0; i < 4; i++) {
      int rbase = row0 + waveM * 64 + i * 16 + qq * 4;
#pragma unroll
      for (int r = 0; r < 4; r++)
        Cf[(size_t)(rbase + r) * N + col] = acc[i][j][r] + bv;
    }
  }
}

// ---------------- chain: LDS-staged, 32 segments, tree-combined 4x4 log-semiring -------
// lpa lives in per-thread registers (statically indexed) -> LDS 37.9 KB -> 4 blocks/CU.
__global__ __launch_bounds__(512) void chain2(
    const float* __restrict__ x, const float* __restrict__ theta,
    const float* __restrict__ lpa, float* __restrict__ logp)
{
  __shared__ float ths[256 * 33];       // theta row, pitch 33
  __shared__ float xs[256];
  __shared__ float TA[32][16];
  __shared__ float TB[16][16];

  const int b = blockIdx.x;
  const int tid = threadIdx.x;
  const float C0 = 0.91893853320467274178f;     // 0.5*log(2*pi)

  const int seg = tid >> 4, e = tid & 15, ii = e >> 2, jj = e & 3;
  const int base = (tid & 63) & ~15;
  const int d0 = 1 + seg * 8;
  const int d1 = min(d0 + 8, Dd - 1);

  // ---- preload this thread's lpa values into registers (static indexing) ----
  float lpr[8];
#pragma unroll
  for (int k = 0; k < 8; k++) {
    int d = d0 + k;
    lpr[k] = lpa[(d <= 254 ? d : 254) * 4 + jj];
  }

  // ---- cooperative stage: theta row (32KB), x row ----
  const float4* src = (const float4*)(theta + (size_t)b * NOUT);
#pragma unroll
  for (int it = 0; it < 4; it++) {
    int t = tid + it * 512;                     // 2048 float4 total
    float4 v = src[t];
    int d = t >> 3, c = (t & 7) * 4;
    float* p = &ths[d * 33 + c];
    p[0] = v.x; p[1] = v.y; p[2] = v.z; p[3] = v.w;
  }
  if (tid < 64) ((float4*)xs)[tid] = ((const float4*)(x + (size_t)b * Dd))[tid];
  __syncthreads();

  // ---- phase 1: 32 segments x ~8 steps, 16 threads per segment ----
  auto stepm = [&](int d, float lp) -> float {
    float mu = ths[d * 33 + e];
    float ls = ths[d * 33 + 16 + e];
    float s  = __expf(ls) + 0.01f;
    float z  = (xs[d] - mu) * __builtin_amdgcn_rcpf(s);
    return -0.5f * z * z - __logf(s) - C0 + lp;
  };

  float T = stepm(d0, lpr[0]);
#pragma unroll
  for (int k = 1; k < 8; k++) {
    int d = d0 + k;
    if (d < d1) {                     // uniform within each 16-thread segment
      float m_ = stepm(d, lpr[k]);
      float v0 = __shfl(T, base + ii * 4 + 0) + __shfl(m_, base + 0 * 4 + jj);
      float v1 = __shfl(T, base + ii * 4 + 1) + __shfl(m_, base + 1 * 4 + jj);
      float v2 = __shfl(T, base + ii * 4 + 2) + __shfl(m_, base + 2 * 4 + jj);
      float v3 = __shfl(T, base + ii * 4 + 3) + __shfl(m_, base + 3 * 4 + jj);
      float mx = fmaxf(fmaxf(v0, v1), fmaxf(v2, v3));
      float s  = __expf(v0 - mx) + __expf(v1 - mx) + __expf(v2 - mx) + __expf(v3 - mx);
      T = mx + __logf(s);
    }
  }
  TA[seg][e] = T;
  __syncthreads();

  // ---- phase 2: binary tree of 4x4 log-semiring matrix products (32 -> 1) ----
  float (*cur)[16] = TA;
  float (*nxt)[16] = TB;
#pragma unroll
  for (int n = 16; n >= 1; n >>= 1) {
    if (tid < n * 16) {
      int p = tid >> 4, ee = tid & 15, i2 = ee >> 2, j2 = ee & 3;
      const float* L = cur[2 * p];
      const float* R = cur[2 * p + 1];
      float v0 = L[i2 * 4 + 0] + R[0 * 4 + j2];
      float v1 = L[i2 * 4 + 1] + R[1 * 4 + j2];
      float v2 = L[i2 * 4 + 2] + R[2 * 4 + j2];
      float v3 = L[i2 * 4 + 3] + R[3 * 4 + j2];
      float mx = fmaxf(fmaxf(v0, v1), fmaxf(v2, v3));
      float ss = __expf(v0 - mx) + __expf(v1 - mx) + __expf(v2 - mx) + __expf(v3 - mx);
      nxt[p][ee] = mx + __logf(ss);
    }
    __syncthreads();
    float (*tmp)[16] = cur; cur = nxt; nxt = tmp;
  }

  // ---- final: logp = LSE_{i,j}( first[i] + P[i][j] + last[j] ) ----
  if (tid < 16) {
    int i = tid >> 2, j = tid & 3;
    float mu0 = ths[i], ls0 = ths[16 + i];                   // d=0, row 0, col i
    float s0 = __expf(ls0) + 0.01f;
    float z0 = (xs[0] - mu0) * __builtin_amdgcn_rcpf(s0);
    float c0 = -0.5f * z0 * z0 - __logf(s0) - C0 + lpa[i];
    float muL = ths[255 * 33 + j * 4];                       // d=255, row j, col 0
    float lsL = ths[255 * 33 + 16 + j * 4];
    float sL = __expf(lsL) + 0.01f;
    float zL = (xs[255] - muL) * __builtin_amdgcn_rcpf(sL);
    float lL = -0.5f * zL * zL - __logf(sL) - C0;
    float v = c0 + cur[0][tid] + lL;
    float mx = fmaxf(v, __shfl_xor(v, 1));
    mx = fmaxf(mx, __shfl_xor(mx, 2));
    mx = fmaxf(mx, __shfl_xor(mx, 4));
    mx = fmaxf(mx, __shfl_xor(mx, 8));
    float ee = __expf(v - mx);
    ee += __shfl_xor(ee, 1);
    ee += __shfl_xor(ee, 2);
    ee += __shfl_xor(ee, 4);
    ee += __shfl_xor(ee, 8);
    if (tid == 0) logp[b] = mx + __logf(ee);
  }
}

extern "C" void kernel_launch(void* const* d_in, const int* in_sizes, int n_in,
                              void* d_out, int out_size, void* d_ws, size_t ws_size,
                              hipStream_t stream)
{
  const float* x    = (const float*)d_in[0];
  const float* W0   = (const float*)d_in[1];
  const float* b0   = (const float*)d_in[2];
  const float* W1   = (const float*)d_in[3];
  const float* b1   = (const float*)d_in[4];
  const float* W2   = (const float*)d_in[5];
  const float* b2   = (const float*)d_in[6];
  const float* Wout = (const float*)d_in[7];
  const float* bout = (const float*)d_in[8];
  const float* ulpa = (const float*)d_in[9];

  float* out   = (float*)d_out;
  float* logp  = out;               // (B,1,1)
  float* theta = out + Bsz;         // (B,D,2,A,A) fp32

  ushort* ws    = (ushort*)d_ws;
  ushort* xb    = ws;                       // 262144
  ushort* w0b   = xb + 262144;              // 131072
  ushort* w1b   = w0b + 131072;             // 262144
  ushort* w2b   = w1b + 262144;             // 262144
  ushort* woutb = w2b + 262144;             // 4194304
  ushort* h0    = woutb + 4194304;          // 524288
  ushort* h1    = h0 + 524288;              // 524288
  ushort* h2    = h1 + 524288;              // 524288
  float*  lpa   = (float*)(h2 + 524288);    // 1020 floats

  prep<<<2497, 256, 0, stream>>>(x, W0, W1, W2, Wout, ulpa,
                                 xb, w0b, w1b, w2b, woutb, lpa);
  gemm_s<Dd><<<dim3(16, 32), 256, 0, stream>>>(xb, w0b, b0, h0);
  gemm_s<Hh><<<dim3(16, 32), 256, 0, stream>>>(h0, w1b, b1, h1);
  gemm_s<Hh><<<dim3(16, 32), 256, 0, stream>>>(h1, w2b, b2, h2);
  gemm_big<<<dim3(NOUT / 128, Bsz / 128), 256, 0, stream>>>(h2, woutb, bout, theta, Bsz, NOUT, Hh);
  chain2<<<Bsz, 512, 0, stream>>>(x, theta, lpa, logp);
}